// Round 14
// baseline (6232.296 us; speedup 1.0000x reference)
//
#include <hip/hip_runtime.h>
#include <math.h>

#define B_  32
#define S_  512
#define H_  1024
#define SENT32 0x7F7F7F7Fu   // bf16 0x7F7F ~ 3.39e38; |h|<1 so unreachable

typedef __attribute__((ext_vector_type(8))) short bf16x8;   // 8 bf16 in 4 VGPRs
typedef __attribute__((ext_vector_type(4))) float f32x4;
typedef __attribute__((ext_vector_type(4))) unsigned int u32x4;

__device__ __forceinline__ unsigned short f2bf(float f) {
  unsigned int u = __float_as_uint(f);
  u = (u + 0x7FFFu + ((u >> 16) & 1u)) >> 16;   // RNE
  return (unsigned short)u;
}

// 16B load, bypass L1 AND L2 (sc0 sc1) -> MALL, agent-coherent. Issued
// without any waitcnt; caller batches many then waits ONCE.
__device__ __forceinline__ void ld4_mall(const unsigned short* p, u32x4& r) {
  asm volatile("global_load_dwordx4 %0, %1, off sc0 sc1" : "=v"(r) : "v"(p));
}
// 4B store, agent-coherent (MALL). Fire-and-forget; its ack is only ever
// awaited inside a subsequent poll's vmcnt(0), never at a barrier.
__device__ __forceinline__ void st_mall_b32(unsigned short* p, unsigned int v) {
  asm volatile("global_store_dword %0, %1, off sc0 sc1" :: "v"(p), "v"(v) : "memory");
}

// Workgroup barrier that drains ONLY lgkmcnt (LDS), not vmcnt: exchange-store
// acks and in-flight poll loads stay outstanding across it.
#define BAR_LGKM() do {                                   \
  __builtin_amdgcn_sched_barrier(0);                      \
  asm volatile("s_waitcnt lgkmcnt(0)" ::: "memory");      \
  __builtin_amdgcn_s_barrier();                           \
  __builtin_amdgcn_sched_barrier(0);                      \
} while (0)

// load 8 consecutive f32 and pack to bf16x8 (RNE; bit-identical to f2bf cast)
__device__ __forceinline__ bf16x8 ld8_f32_to_bf16(const float* p) {
  float4 a = *(const float4*)p;
  float4 b = *(const float4*)(p + 4);
  union { unsigned short s[8]; bf16x8 v; } u;
  u.s[0] = f2bf(a.x); u.s[1] = f2bf(a.y); u.s[2] = f2bf(a.z); u.s[3] = f2bf(a.w);
  u.s[4] = f2bf(b.x); u.s[5] = f2bf(b.y); u.s[6] = f2bf(b.z); u.s[7] = f2bf(b.w);
  return u.v;
}

// x (B,S,512) fp32 -> xtm (S,B,512) bf16 (one-time; R12 proved per-step
// f32 x reads cost +250-320MB HBM)
__global__ void cast_transpose_x(const float* __restrict__ x, unsigned short* __restrict__ xtm) {
  int s = blockIdx.x & 511, b = blockIdx.x >> 9;   // grid 16384
  int k = threadIdx.x * 4;                          // 128 threads
  float4 v = *(const float4*)(x + ((size_t)b * S_ + s) * 512 + k);
  ushort4 o = { f2bf(v.x), f2bf(v.y), f2bf(v.z), f2bf(v.w) };
  *(ushort4*)(xtm + ((size_t)s * B_ + b) * 512 + k) = o;
}

// ---------------- fused 2-layer persistent GRU + lagging projection ----------------
// Grid 160 x 512 threads (8 waves). Blocks 0-63: layer 0; 64-127: layer 1;
// 128-159: projection (out = y1 @ Wlin^T + blin), trailing the L1 wavefront.
// SYNC (R9, verified): exchange hx[t][blk][b][16feat] -- each producer block
// owns a contiguous line-aligned 1KB region per step (single-writer lines).
// Buffers poisoned 0x7F; consumers fetch fragments as batched MALL loads +
// ONE vmcnt(0), sentinel-check (store IS the signal).
// R14: epilogue off the h-critical-path.
//  - part[] double-buffered (2x48KB, 1 block/CU) -> ONE barrier per step.
//  - epilogue on waves 0-3 only (256 thr x 2 outputs, one u32/thread, direct
//    store -- no shfl; R10's shfl-gather delay avoided).
//  - h-waves: after the barrier, s_sleep(16) (~0.43us ~= epilogue+store
//    issue) THEN poll hxbuf[t] -- first attempt lands as producers' stores
//    allocate the lines, avoiding R6/R10's no-allocate HBM miss storm.
// Deadlock-free: x-waves' epilogue depends only on part[t&1] (pre-barrier);
// polls only target strictly-earlier producers.

__global__ __launch_bounds__(512, 2)
void gru_fused(const float* __restrict__ wih0, const float* __restrict__ whh0,
               const float* __restrict__ b0,
               const float* __restrict__ wih1, const float* __restrict__ whh1,
               const float* __restrict__ b1,
               const unsigned short* __restrict__ xtm,
               const float* __restrict__ wlin, const float* __restrict__ blin,
               unsigned short* __restrict__ hx0, unsigned short* __restrict__ hx1,
               float* __restrict__ out,
               float* __restrict__ hlast0, float* __restrict__ hlast1) {
  __shared__ __align__(16) float part[2][8 * 2 * 3 * 64 * 4];   // 2 x 48 KB
  const int tid  = threadIdx.x;
  const int lane = tid & 63;
  const int w    = tid >> 6;          // 0..7
  const int r16  = lane & 15;
  const int q    = lane >> 4;

  union AU { unsigned int dd[4]; u32x4 u4; bf16x8 v; };

  // ================= projection path (blocks 128-159), R13 verbatim =================
  if (blockIdx.x >= 128) {
    const int nj0 = ((int)blockIdx.x - 128) * 16;
    const int kbase = w * 128;          // 8 waves x 128 cols = K=1024
    const int blkbase = kbase >> 4;
    bf16x8 bwp[4];
#pragma unroll
    for (int c = 0; c < 4; ++c)
      bwp[c] = ld8_f32_to_bf16(wlin + (size_t)(nj0 + r16) * H_ + kbase + c * 32 + q * 8);
    const int eb = tid >> 4, ejj = tid & 15;
    const int em = eb >> 4, eq2 = (eb >> 2) & 3, ereg = eb & 3;
    const float bl = blin[nj0 + ejj];
    const int hxLaneOff = ((q >> 1) * 512) + r16 * 16 + (q & 1) * 8;
    float* pb = part[0];

    for (int t = 0; t < S_; ++t) {
      const unsigned short* hp = hx1 + ((size_t)t * 64 + blkbase) * 512 + hxLaneOff;
      AU a0[4], a1[4];
      int spins = 0;
      for (;;) {
#pragma unroll
        for (int c = 0; c < 4; ++c) {
          ld4_mall(hp + c * 1024, a0[c].u4);          // rows 0-15
          ld4_mall(hp + c * 1024 + 256, a1[c].u4);    // rows 16-31
        }
        asm volatile("s_waitcnt vmcnt(0)"
          : "+v"(a0[0].u4), "+v"(a0[1].u4), "+v"(a0[2].u4), "+v"(a0[3].u4),
            "+v"(a1[0].u4), "+v"(a1[1].u4), "+v"(a1[2].u4), "+v"(a1[3].u4)
          :: "memory");
        __builtin_amdgcn_sched_barrier(0);
        int ok = 1;
#pragma unroll
        for (int c = 0; c < 4; ++c)
#pragma unroll
          for (int d = 0; d < 4; ++d)
            ok &= (a0[c].dd[d] != SENT32) & (a1[c].dd[d] != SENT32);
        if (__all(ok)) break;
        if (++spins > (1 << 16)) break;    // hang-safety only (~55ms cap)
        __builtin_amdgcn_s_sleep(32);      // ~0.85us: stay BEHIND the wavefront
      }

      f32x4 acc[2];
#pragma unroll
      for (int m = 0; m < 2; ++m)
#pragma unroll
        for (int u = 0; u < 4; ++u) acc[m][u] = 0.f;
#pragma unroll
      for (int c = 0; c < 4; ++c) {
        acc[0] = __builtin_amdgcn_mfma_f32_16x16x32_bf16(a0[c].v, bwp[c], acc[0], 0, 0, 0);
        acc[1] = __builtin_amdgcn_mfma_f32_16x16x32_bf16(a1[c].v, bwp[c], acc[1], 0, 0, 0);
      }
#pragma unroll
      for (int m = 0; m < 2; ++m)
        *(f32x4*)&part[0][((w * 2 + m) * 64 + lane) * 4] = acc[m];
      BAR_LGKM();
      {
        float s = 0.f;
#pragma unroll
        for (int ww = 0; ww < 8; ++ww)
          s += pb[((ww * 2 + em) * 64 + eq2 * 16 + ejj) * 4 + ereg];
        out[((size_t)eb * S_ + t) * 512 + nj0 + ejj] = s + bl;
      }
      BAR_LGKM();
    }
    return;
  }

  // ================= recurrence path (blocks 0-127) =================
  const bool L1  = blockIdx.x >= 64;
  const int  j0  = (L1 ? (int)blockIdx.x - 64 : (int)blockIdx.x) * 16;
  const int  myblk = j0 >> 4;
  const bool hiw = w >= 4;

  // per-wave operand plan (weights f32; converted once below)
  const float* Wsrc;
  int wstride, kbase, ncha;
  if (!L1) {
    if (!hiw) { Wsrc = wih0; wstride = 512;  kbase = w * 128;       ncha = 4; }
    else      { Wsrc = whh0; wstride = 1024; kbase = (w - 4) * 256; ncha = 8; }
  } else {
    if (!hiw) { Wsrc = wih1; wstride = 1024; kbase = w * 256;       ncha = 8; }
    else      { Wsrc = whh1; wstride = 1024; kbase = (w - 4) * 256; ncha = 8; }
  }
  const int blkbase = kbase >> 4;

  // B-frags -> registers, once (f32 -> bf16 in-register, bit-identical)
  bf16x8 bw[3][8];
#pragma unroll
  for (int g = 0; g < 3; ++g)
#pragma unroll
    for (int c = 0; c < 8; ++c)
      if (c < ncha)
        bw[g][c] = ld8_f32_to_bf16(Wsrc + (size_t)(g * H_ + j0 + r16) * wstride + kbase + c * 32 + q * 8);

  // epilogue coords (waves 0-3, 256 threads x 2 outputs; one u32/thread)
  const int eb  = tid >> 3;           // 0..31 (valid for tid<256)
  const int ejp = (tid & 7) * 2;      // 0,2,..,14
  const int em  = eb >> 4, eq2 = (eb >> 2) & 3, ereg = eb & 3;
  const float* bias = L1 ? b1 : b0;
  float brv[2], bzv[2], bnv[2], phv[2] = {0.f, 0.f};
  if (tid < 256) {
#pragma unroll
    for (int e = 0; e < 2; ++e) {
      brv[e] = bias[j0 + ejp + e];
      bzv[e] = bias[H_ + j0 + ejp + e];
      bnv[e] = bias[2 * H_ + j0 + ejp + e];
    }
  }

  unsigned short* hxbuf = L1 ? hx1 : hx0;
  float*          hlast = L1 ? hlast1 : hlast0;

  const int hxLaneOff = ((q >> 1) * 512) + r16 * 16 + (q & 1) * 8;

  AU a0[8], a1[8];

  // poll helper: batched agent-coherent fetch, ONE vmcnt per iteration
  auto pollFetch = [&](const unsigned short* hp, bool delayedFirst) {
    if (delayedFirst) __builtin_amdgcn_s_sleep(16);   // ~0.43us: let producers store
    int spins = 0;
    for (;;) {
#pragma unroll
      for (int c = 0; c < 8; ++c) {
        ld4_mall(hp + c * 1024, a0[c].u4);          // rows 0-15 (r16)
        ld4_mall(hp + c * 1024 + 256, a1[c].u4);    // rows 16-31
      }
      asm volatile("s_waitcnt vmcnt(0)"
        : "+v"(a0[0].u4), "+v"(a0[1].u4), "+v"(a0[2].u4), "+v"(a0[3].u4),
          "+v"(a0[4].u4), "+v"(a0[5].u4), "+v"(a0[6].u4), "+v"(a0[7].u4),
          "+v"(a1[0].u4), "+v"(a1[1].u4), "+v"(a1[2].u4), "+v"(a1[3].u4),
          "+v"(a1[4].u4), "+v"(a1[5].u4), "+v"(a1[6].u4), "+v"(a1[7].u4)
        :: "memory");
      __builtin_amdgcn_sched_barrier(0);
      int ok = 1;
#pragma unroll
      for (int c = 0; c < 8; ++c)
#pragma unroll
        for (int d = 0; d < 4; ++d)
          ok &= (a0[c].dd[d] != SENT32) & (a1[c].dd[d] != SENT32);
      if (__all(ok)) break;
      if (++spins > (1 << 20)) break;    // hang-safety only
      if (spins > 8) __builtin_amdgcn_s_sleep(1);
    }
  };
  auto plainX = [&](int t) {
    const unsigned short* ap0 = xtm + (size_t)t * B_ * 512 + (size_t)r16 * 512 + kbase + q * 8;
    const unsigned short* ap1 = ap0 + 16 * 512;
#pragma unroll
    for (int c = 0; c < 8; ++c) if (c < ncha) {
      a0[c].v = *(const bf16x8*)(ap0 + c * 32);
      a1[c].v = *(const bf16x8*)(ap1 + c * 32);
    }
  };

  // ---- prologue: A(0) ----
  if (!hiw) {
    if (!L1) plainX(0);
    else     pollFetch(hx0 + ((size_t)0 * 64 + blkbase) * 512 + hxLaneOff, false);
  } else {
#pragma unroll
    for (int c = 0; c < 8; ++c)
#pragma unroll
      for (int d = 0; d < 4; ++d) { a0[c].dd[d] = 0u; a1[c].dd[d] = 0u; }
  }

  for (int t = 0; t < S_; ++t) {
    // ---- MFMA(t) from prefetched regs ----
    f32x4 acc[2][3];
#pragma unroll
    for (int m = 0; m < 2; ++m)
#pragma unroll
      for (int g = 0; g < 3; ++g)
#pragma unroll
        for (int u = 0; u < 4; ++u) acc[m][g][u] = 0.f;

#pragma unroll
    for (int c = 0; c < 8; ++c) if (c < ncha)
#pragma unroll
      for (int g = 0; g < 3; ++g) {
        acc[0][g] = __builtin_amdgcn_mfma_f32_16x16x32_bf16(a0[c].v, bw[g][c], acc[0][g], 0, 0, 0);
        acc[1][g] = __builtin_amdgcn_mfma_f32_16x16x32_bf16(a1[c].v, bw[g][c], acc[1][g], 0, 0, 0);
      }

    float* pb = part[t & 1];
#pragma unroll
    for (int m = 0; m < 2; ++m)
#pragma unroll
      for (int g = 0; g < 3; ++g)
        *(f32x4*)&pb[(((w * 2 + m) * 3 + g) * 64 + lane) * 4] = acc[m][g];
    BAR_LGKM();                       // the ONLY barrier per step

    if (tid < 256) {
      // ---- epilogue(t): 256 threads x 2 outputs; one u32 store/thread ----
      float hv2[2];
#pragma unroll
      for (int e = 0; e < 2; ++e) {
        int jj = ejp + e;
        float hr = 0.f, hz = 0.f, nx = 0.f, nh = 0.f;
#pragma unroll
        for (int ww = 0; ww < 8; ++ww) {
          int base = (ww * 2 + em) * 3;
          float vr = pb[((base + 0) * 64 + eq2 * 16 + jj) * 4 + ereg];
          float vz = pb[((base + 1) * 64 + eq2 * 16 + jj) * 4 + ereg];
          float vn = pb[((base + 2) * 64 + eq2 * 16 + jj) * 4 + ereg];
          hr += vr; hz += vz;
          if (ww < 4) nx += vn; else nh += vn;
        }
        float r  = __builtin_amdgcn_rcpf(1.f + __expf(-(hr + brv[e])));
        float z  = __builtin_amdgcn_rcpf(1.f + __expf(-(hz + bzv[e])));
        float a2 = nx + bnv[e] + nh + r * nh;
        float nn = 1.f - 2.f * __builtin_amdgcn_rcpf(__expf(2.f * a2) + 1.f);  // tanh
        float hv = (1.f - z) * nn + z * phv[e];
        phv[e] = hv; hv2[e] = hv;
      }
      unsigned int pk = (unsigned int)f2bf(hv2[0]) | ((unsigned int)f2bf(hv2[1]) << 16);
      st_mall_b32(hxbuf + ((size_t)t * 64 + myblk) * 512 + eb * 16 + ejp, pk);
      if (t == S_ - 1) {
        hlast[eb * H_ + j0 + ejp]     = hv2[0];
        hlast[eb * H_ + j0 + ejp + 1] = hv2[1];
      }
      // prefetch A(t+1) for x-waves
      if (t < S_ - 1) {
        if (!L1) plainX(t + 1);
        else     pollFetch(hx0 + ((size_t)(t + 1) * 64 + blkbase) * 512 + hxLaneOff, false);
      }
    } else {
      // ---- h-waves: no epilogue; delayed poll of hxbuf[t] (for step t+1) ----
      if (t < S_ - 1)
        pollFetch(hxbuf + ((size_t)t * 64 + blkbase) * 512 + hxLaneOff, true);
    }
    // no trailing barrier: part[] double-buffered; next write to part[t&1]
    // is step t+2, gated by barrier(t+1), which x-waves reach only after
    // finishing their epilogue(t) reads.
  }
}

extern "C" void kernel_launch(void* const* d_in, const int* in_sizes, int n_in,
                              void* d_out, int out_size, void* d_ws, size_t ws_size,
                              hipStream_t stream) {
  const float* x    = (const float*)d_in[0];
  const float* Wih0 = (const float*)d_in[1];
  const float* Whh0 = (const float*)d_in[2];
  const float* b0   = (const float*)d_in[3];
  const float* Wih1 = (const float*)d_in[4];
  const float* Whh1 = (const float*)d_in[5];
  const float* b1   = (const float*)d_in[6];
  const float* Wlin = (const float*)d_in[7];
  const float* blin = (const float*)d_in[8];
  float* out = (float*)d_out;

  char* p = (char*)d_ws;
  size_t off = 0;
  auto alloc = [&](size_t bytes) { void* r = p + off; off += (bytes + 255) & ~(size_t)255; return r; };

  unsigned short* xtm = (unsigned short*)alloc((size_t)8388608 * 2);   // (S,B,512) bf16
  unsigned short* hx0 = (unsigned short*)alloc((size_t)16777216 * 2);  // [S][64][32][16] bf16
  unsigned short* hx1 = (unsigned short*)alloc((size_t)16777216 * 2);  // [S][64][32][16] bf16

  // poison exchange buffers: 0x7F7F bf16 sentinel (unreachable since |h|<1)
  (void)hipMemsetAsync(hx0, 0x7F, (size_t)16777216 * 2, stream);
  (void)hipMemsetAsync(hx1, 0x7F, (size_t)16777216 * 2, stream);

  cast_transpose_x<<<16384, 128, 0, stream>>>(x, xtm);

  float* hlast0 = out + 8388608;
  float* hlast1 = out + 8388608 + B_ * H_;

  gru_fused<<<160, 512, 0, stream>>>(Wih0, Whh0, b0, Wih1, Whh1, b1,
                                     xtm, Wlin, blin, hx0, hx1, out,
                                     hlast0, hlast1);
}

// Round 15
// 1799.828 us; speedup vs baseline: 3.4627x; 3.4627x over previous
//
#include <hip/hip_runtime.h>
#include <math.h>

#define B_  32
#define S_  512
#define H_  1024
#define SENT32 0x7F7F7F7Fu   // bf16 0x7F7F ~ 3.39e38; |h|<1 so unreachable
#define NSLAB 64             // cyclic hx slabs per layer (4MB -> MALL-hot)
#define PAHEAD 32            // producer re-poisons slab (t+PAHEAD)%NSLAB

typedef __attribute__((ext_vector_type(8))) short bf16x8;   // 8 bf16 in 4 VGPRs
typedef __attribute__((ext_vector_type(4))) float f32x4;
typedef __attribute__((ext_vector_type(4))) unsigned int u32x4;

__device__ __forceinline__ unsigned short f2bf(float f) {
  unsigned int u = __float_as_uint(f);
  u = (u + 0x7FFFu + ((u >> 16) & 1u)) >> 16;   // RNE
  return (unsigned short)u;
}

// 16B load, bypass L1 AND L2 (sc0 sc1) -> MALL, agent-coherent. Issued
// without any waitcnt; caller batches many then waits ONCE.
__device__ __forceinline__ void ld4_mall(const unsigned short* p, u32x4& r) {
  asm volatile("global_load_dwordx4 %0, %1, off sc0 sc1" : "=v"(r) : "v"(p));
}
// 4B store, agent-coherent (MALL). Fire-and-forget; its ack is only ever
// awaited inside a subsequent poll's vmcnt(0), never at a barrier.
__device__ __forceinline__ void st_mall_b32(unsigned short* p, unsigned int v) {
  asm volatile("global_store_dword %0, %1, off sc0 sc1" :: "v"(p), "v"(v) : "memory");
}

// Workgroup barrier that drains ONLY lgkmcnt (LDS), not vmcnt: exchange-store
// acks and in-flight poll loads stay outstanding across it.
#define BAR_LGKM() do {                                   \
  __builtin_amdgcn_sched_barrier(0);                      \
  asm volatile("s_waitcnt lgkmcnt(0)" ::: "memory");      \
  __builtin_amdgcn_s_barrier();                           \
  __builtin_amdgcn_sched_barrier(0);                      \
} while (0)

// load 8 consecutive f32 and pack to bf16x8 (RNE; bit-identical to f2bf cast)
__device__ __forceinline__ bf16x8 ld8_f32_to_bf16(const float* p) {
  float4 a = *(const float4*)p;
  float4 b = *(const float4*)(p + 4);
  union { unsigned short s[8]; bf16x8 v; } u;
  u.s[0] = f2bf(a.x); u.s[1] = f2bf(a.y); u.s[2] = f2bf(a.z); u.s[3] = f2bf(a.w);
  u.s[4] = f2bf(b.x); u.s[5] = f2bf(b.y); u.s[6] = f2bf(b.z); u.s[7] = f2bf(b.w);
  return u.v;
}

// x (B,S,512) fp32 -> xtm (S,B,512) bf16 (one-time; R12 proved per-step
// f32 x reads cost +250-320MB HBM)
__global__ void cast_transpose_x(const float* __restrict__ x, unsigned short* __restrict__ xtm) {
  int s = blockIdx.x & 511, b = blockIdx.x >> 9;   // grid 16384
  int k = threadIdx.x * 4;                          // 128 threads
  float4 v = *(const float4*)(x + ((size_t)b * S_ + s) * 512 + k);
  ushort4 o = { f2bf(v.x), f2bf(v.y), f2bf(v.z), f2bf(v.w) };
  *(ushort4*)(xtm + ((size_t)s * B_ + b) * 512 + k) = o;
}

// ---------------- fused 2-layer persistent GRU + lagging projection ----------------
// Grid 160 x 512 threads (8 waves). Blocks 0-63: layer 0; 64-127: layer 1;
// 128-159: projection (out = y1 @ Wlin^T + blin), trailing the L1 wavefront.
// SYNC (R9/R13, verified): exchange hx[slab][blk][b][16feat] -- each producer
// block owns a contiguous line-aligned 1KB region per step (single-writer
// lines). Poisoned 0x7F; consumers fetch fragments as batched MALL loads +
// ONE vmcnt(0), sentinel-check (store IS the signal). Polls ONLY at the
// aligned position (after 2nd barrier) -- early polling refuted 3x (R6/R10/R14).
// R15: hx is a CYCLIC 64-slab buffer per layer (4MB, permanently MALL-hot;
// R13's 64MB streaming buffer made failed polls HBM misses -- FETCH 488MB).
// Re-poison: producer block re-poisons slab (t+32)%64 (its own 1KB region)
// during the step-t epilogue. Safety: L0/L1 peer skew <=1 step (each step
// needs ALL peers' previous step); L1/proj lags are poll-gated and << 32
// steps (~110us margin); poison(t) -> data(t+32) same-thread same-address
// ordering guaranteed by per-step vmcnt drains.

__global__ __launch_bounds__(512, 2)
void gru_fused(const float* __restrict__ wih0, const float* __restrict__ whh0,
               const float* __restrict__ b0,
               const float* __restrict__ wih1, const float* __restrict__ whh1,
               const float* __restrict__ b1,
               const unsigned short* __restrict__ xtm,
               const float* __restrict__ wlin, const float* __restrict__ blin,
               unsigned short* __restrict__ hx0, unsigned short* __restrict__ hx1,
               float* __restrict__ out,
               float* __restrict__ hlast0, float* __restrict__ hlast1) {
  __shared__ __align__(16) float part[8 * 2 * 3 * 64 * 4];   // 48 KB [w][m][g][lane][reg]
  const int tid  = threadIdx.x;
  const int lane = tid & 63;
  const int w    = tid >> 6;          // 0..7
  const int r16  = lane & 15;
  const int q    = lane >> 4;

  union AU { unsigned int dd[4]; u32x4 u4; bf16x8 v; };

  // ================= projection path (blocks 128-159) =================
  if (blockIdx.x >= 128) {
    const int nj0 = ((int)blockIdx.x - 128) * 16;
    const int kbase = w * 128;          // 8 waves x 128 cols = K=1024
    const int blkbase = kbase >> 4;
    bf16x8 bwp[4];
#pragma unroll
    for (int c = 0; c < 4; ++c)
      bwp[c] = ld8_f32_to_bf16(wlin + (size_t)(nj0 + r16) * H_ + kbase + c * 32 + q * 8);
    const int eb = tid >> 4, ejj = tid & 15;
    const int em = eb >> 4, eq2 = (eb >> 2) & 3, ereg = eb & 3;
    const float bl = blin[nj0 + ejj];
    const int hxLaneOff = ((q >> 1) * 512) + r16 * 16 + (q & 1) * 8;

    for (int t = 0; t < S_; ++t) {
      const unsigned short* hp = hx1 + ((size_t)(t & (NSLAB - 1)) * 64 + blkbase) * 512 + hxLaneOff;
      AU a0[4], a1[4];
      int spins = 0;
      for (;;) {
#pragma unroll
        for (int c = 0; c < 4; ++c) {
          ld4_mall(hp + c * 1024, a0[c].u4);          // rows 0-15
          ld4_mall(hp + c * 1024 + 256, a1[c].u4);    // rows 16-31
        }
        asm volatile("s_waitcnt vmcnt(0)"
          : "+v"(a0[0].u4), "+v"(a0[1].u4), "+v"(a0[2].u4), "+v"(a0[3].u4),
            "+v"(a1[0].u4), "+v"(a1[1].u4), "+v"(a1[2].u4), "+v"(a1[3].u4)
          :: "memory");
        __builtin_amdgcn_sched_barrier(0);
        int ok = 1;
#pragma unroll
        for (int c = 0; c < 4; ++c)
#pragma unroll
          for (int d = 0; d < 4; ++d)
            ok &= (a0[c].dd[d] != SENT32) & (a1[c].dd[d] != SENT32);
        if (__all(ok)) break;
        if (++spins > (1 << 16)) break;    // hang-safety only (~55ms cap)
        __builtin_amdgcn_s_sleep(32);      // ~0.85us: stay BEHIND the wavefront
      }

      f32x4 acc[2];
#pragma unroll
      for (int m = 0; m < 2; ++m)
#pragma unroll
        for (int u = 0; u < 4; ++u) acc[m][u] = 0.f;
#pragma unroll
      for (int c = 0; c < 4; ++c) {
        acc[0] = __builtin_amdgcn_mfma_f32_16x16x32_bf16(a0[c].v, bwp[c], acc[0], 0, 0, 0);
        acc[1] = __builtin_amdgcn_mfma_f32_16x16x32_bf16(a1[c].v, bwp[c], acc[1], 0, 0, 0);
      }
#pragma unroll
      for (int m = 0; m < 2; ++m)
        *(f32x4*)&part[((w * 2 + m) * 64 + lane) * 4] = acc[m];
      BAR_LGKM();
      {
        float s = 0.f;
#pragma unroll
        for (int ww = 0; ww < 8; ++ww)
          s += part[((ww * 2 + em) * 64 + eq2 * 16 + ejj) * 4 + ereg];
        out[((size_t)eb * S_ + t) * 512 + nj0 + ejj] = s + bl;
      }
      BAR_LGKM();
    }
    return;
  }

  // ================= recurrence path (blocks 0-127), R13 core =================
  const bool L1  = blockIdx.x >= 64;
  const int  j0  = (L1 ? (int)blockIdx.x - 64 : (int)blockIdx.x) * 16;
  const int  myblk = j0 >> 4;
  const bool hiw = w >= 4;

  // per-wave operand plan (weights f32; converted once below)
  const float* Wsrc;
  int wstride, kbase, ncha;
  if (!L1) {
    if (!hiw) { Wsrc = wih0; wstride = 512;  kbase = w * 128;       ncha = 4; }
    else      { Wsrc = whh0; wstride = 1024; kbase = (w - 4) * 256; ncha = 8; }
  } else {
    if (!hiw) { Wsrc = wih1; wstride = 1024; kbase = w * 256;       ncha = 8; }
    else      { Wsrc = whh1; wstride = 1024; kbase = (w - 4) * 256; ncha = 8; }
  }
  const int blkbase = kbase >> 4;

  // B-frags -> registers, once (f32 -> bf16 in-register, bit-identical)
  bf16x8 bw[3][8];
#pragma unroll
  for (int g = 0; g < 3; ++g)
#pragma unroll
    for (int c = 0; c < 8; ++c)
      if (c < ncha)
        bw[g][c] = ld8_f32_to_bf16(Wsrc + (size_t)(g * H_ + j0 + r16) * wstride + kbase + c * 32 + q * 8);

  // epilogue coords: 512 threads, 1 output (batch eb, feature ejj) each
  const int eb  = tid >> 4;       // 0..31
  const int ejj = tid & 15;       // 0..15
  const int em  = eb >> 4, eq2 = (eb >> 2) & 3, ereg = eb & 3;
  const float* bias = L1 ? b1 : b0;
  const float brv = bias[j0 + ejj];
  const float bzv = bias[H_ + j0 + ejj];
  const float bnv = bias[2 * H_ + j0 + ejj];
  float phv = 0.f;

  unsigned short* hxbuf = L1 ? hx1 : hx0;
  float*          hlast = L1 ? hlast1 : hlast0;

  const int hxLaneOff = ((q >> 1) * 512) + r16 * 16 + (q & 1) * 8;

  for (int t = 0; t < S_; ++t) {
    // ---- A-frags ----
    AU a0[8], a1[8];
    if (!hiw && !L1) {
      // L0 x-waves: plain cached bf16 loads from pre-transposed xtm
      const unsigned short* ap0 = xtm + (size_t)t * B_ * 512 + (size_t)r16 * 512 + kbase + q * 8;
      const unsigned short* ap1 = ap0 + 16 * 512;
#pragma unroll
      for (int c = 0; c < 8; ++c) if (c < ncha) {
        a0[c].v = *(const bf16x8*)(ap0 + c * 32);
        a1[c].v = *(const bf16x8*)(ap1 + c * 32);
      }
    } else if (hiw && t == 0) {
      // h[-1] = 0
#pragma unroll
      for (int c = 0; c < 8; ++c)
#pragma unroll
        for (int d = 0; d < 4; ++d) { a0[c].dd[d] = 0u; a1[c].dd[d] = 0u; }
    } else {
      // polled fetch (L1 x-waves on hx0 slab t; h-waves on hxbuf slab t-1)
      const unsigned short* hp = (!hiw)
        ? hx0   + ((size_t)(t & (NSLAB - 1)) * 64 + blkbase) * 512 + hxLaneOff
        : hxbuf + ((size_t)((t - 1) & (NSLAB - 1)) * 64 + blkbase) * 512 + hxLaneOff;
      int spins = 0;
      for (;;) {
#pragma unroll
        for (int c = 0; c < 8; ++c) {
          ld4_mall(hp + c * 1024, a0[c].u4);          // rows 0-15 (r16)
          ld4_mall(hp + c * 1024 + 256, a1[c].u4);    // rows 16-31
        }
        asm volatile("s_waitcnt vmcnt(0)"
          : "+v"(a0[0].u4), "+v"(a0[1].u4), "+v"(a0[2].u4), "+v"(a0[3].u4),
            "+v"(a0[4].u4), "+v"(a0[5].u4), "+v"(a0[6].u4), "+v"(a0[7].u4),
            "+v"(a1[0].u4), "+v"(a1[1].u4), "+v"(a1[2].u4), "+v"(a1[3].u4),
            "+v"(a1[4].u4), "+v"(a1[5].u4), "+v"(a1[6].u4), "+v"(a1[7].u4)
          :: "memory");
        __builtin_amdgcn_sched_barrier(0);
        int ok = 1;
#pragma unroll
        for (int c = 0; c < 8; ++c)
#pragma unroll
          for (int d = 0; d < 4; ++d)
            ok &= (a0[c].dd[d] != SENT32) & (a1[c].dd[d] != SENT32);
        if (__all(ok)) break;
        if (++spins > (1 << 20)) break;    // hang-safety only
        if (spins > 8) __builtin_amdgcn_s_sleep(1);
      }
    }

    f32x4 acc[2][3];
#pragma unroll
    for (int m = 0; m < 2; ++m)
#pragma unroll
      for (int g = 0; g < 3; ++g)
#pragma unroll
        for (int u = 0; u < 4; ++u) acc[m][g][u] = 0.f;

#pragma unroll
    for (int c = 0; c < 8; ++c) if (c < ncha)
#pragma unroll
      for (int g = 0; g < 3; ++g) {
        acc[0][g] = __builtin_amdgcn_mfma_f32_16x16x32_bf16(a0[c].v, bw[g][c], acc[0][g], 0, 0, 0);
        acc[1][g] = __builtin_amdgcn_mfma_f32_16x16x32_bf16(a1[c].v, bw[g][c], acc[1][g], 0, 0, 0);
      }

#pragma unroll
    for (int m = 0; m < 2; ++m)
#pragma unroll
      for (int g = 0; g < 3; ++g)
        *(f32x4*)&part[(((w * 2 + m) * 3 + g) * 64 + lane) * 4] = acc[m][g];
    BAR_LGKM();                       // LDS writes visible; no vmem drain

    // ---- epilogue: 512 threads x 1 output; packed u32 store is the signal ----
    {
      float hr = 0.f, hz = 0.f, nx = 0.f, nh = 0.f;
#pragma unroll
      for (int ww = 0; ww < 8; ++ww) {
        int base = (ww * 2 + em) * 3;
        float vr = part[((base + 0) * 64 + eq2 * 16 + ejj) * 4 + ereg];
        float vz = part[((base + 1) * 64 + eq2 * 16 + ejj) * 4 + ereg];
        float vn = part[((base + 2) * 64 + eq2 * 16 + ejj) * 4 + ereg];
        hr += vr; hz += vz;
        if (ww < 4) nx += vn; else nh += vn;
      }
      float r  = __builtin_amdgcn_rcpf(1.f + __expf(-(hr + brv)));
      float z  = __builtin_amdgcn_rcpf(1.f + __expf(-(hz + bzv)));
      float a2 = nx + bnv + nh + r * nh;
      float nn = 1.f - 2.f * __builtin_amdgcn_rcpf(__expf(2.f * a2) + 1.f);  // tanh
      float hv = (1.f - z) * nn + z * phv;
      phv = hv;
      float other = __shfl_xor(hv, 1);   // partner tid^1 = same batch, ejj^1
      if ((ejj & 1) == 0) {
        unsigned int pk = (unsigned int)f2bf(hv) | ((unsigned int)f2bf(other) << 16);
        // single-writer, line-aligned 1KB region per (slab, block)
        st_mall_b32(hxbuf + ((size_t)(t & (NSLAB - 1)) * 64 + myblk) * 512 + eb * 16 + ejj, pk);
        // re-poison slab (t+PAHEAD)%NSLAB (written at t-32, consumed long ago)
        st_mall_b32(hxbuf + ((size_t)((t + PAHEAD) & (NSLAB - 1)) * 64 + myblk) * 512 + eb * 16 + ejj, SENT32);
        if (t == S_ - 1) {
          hlast[eb * H_ + j0 + ejj]     = hv;
          hlast[eb * H_ + j0 + ejj + 1] = other;
        }
      }
    }
    BAR_LGKM();                       // part[] reads done; store acks NOT drained
  }
}

extern "C" void kernel_launch(void* const* d_in, const int* in_sizes, int n_in,
                              void* d_out, int out_size, void* d_ws, size_t ws_size,
                              hipStream_t stream) {
  const float* x    = (const float*)d_in[0];
  const float* Wih0 = (const float*)d_in[1];
  const float* Whh0 = (const float*)d_in[2];
  const float* b0   = (const float*)d_in[3];
  const float* Wih1 = (const float*)d_in[4];
  const float* Whh1 = (const float*)d_in[5];
  const float* b1   = (const float*)d_in[6];
  const float* Wlin = (const float*)d_in[7];
  const float* blin = (const float*)d_in[8];
  float* out = (float*)d_out;

  char* p = (char*)d_ws;
  size_t off = 0;
  auto alloc = [&](size_t bytes) { void* r = p + off; off += (bytes + 255) & ~(size_t)255; return r; };

  unsigned short* xtm = (unsigned short*)alloc((size_t)8388608 * 2);   // (S,B,512) bf16
  // cyclic exchange: [NSLAB][64 blk][32 b][16 feat] bf16 = 4MB per layer
  unsigned short* hx0 = (unsigned short*)alloc((size_t)NSLAB * 64 * 512 * 2);
  unsigned short* hx1 = (unsigned short*)alloc((size_t)NSLAB * 64 * 512 * 2);

  // poison exchange buffers: 0x7F7F bf16 sentinel (unreachable since |h|<1)
  (void)hipMemsetAsync(hx0, 0x7F, (size_t)NSLAB * 64 * 512 * 2, stream);
  (void)hipMemsetAsync(hx1, 0x7F, (size_t)NSLAB * 64 * 512 * 2, stream);

  cast_transpose_x<<<16384, 128, 0, stream>>>(x, xtm);

  float* hlast0 = out + 8388608;
  float* hlast1 = out + 8388608 + B_ * H_;

  gru_fused<<<160, 512, 0, stream>>>(Wih0, Whh0, b0, Wih1, Whh1, b1,
                                     xtm, Wlin, blin, hx0, hx1, out,
                                     hlast0, hlast1);
}